// Round 1
// baseline (120.121 us; speedup 1.0000x reference)
//
#include <hip/hip_runtime.h>
#include <math.h>

#define H 2048
#define V 50257
#define M 64

// ---------- wave-64 reduction helpers ----------
__device__ inline float wred_sum(float v) {
#pragma unroll
    for (int o = 32; o >= 1; o >>= 1) v += __shfl_down(v, o);
    return v;  // lane 0 holds the sum
}

// ---------- K1: attention scores: score[m] = attn_w[m,:] . concat(emb_row, h0) + attn_b[m]
__global__ void k_scores(const int* __restrict__ tok, const float* __restrict__ hidden,
                         const float* __restrict__ emb, const float* __restrict__ attn_w,
                         const float* __restrict__ attn_b, float* __restrict__ scores) {
    const int m = blockIdx.x;         // 64 blocks
    const int t = threadIdx.x;        // 256 threads
    const float* erow = emb + (size_t)tok[0] * H;
    const float4* w4 = (const float4*)(attn_w + (size_t)m * 2 * H);
    float acc = 0.f;
    // 2H = 4096 floats = 1024 float4
    for (int i = t; i < 1024; i += 256) {
        float4 w = w4[i];
        int k = i * 4;
        float4 c = (k < H) ? *(const float4*)(erow + k)
                           : *(const float4*)(hidden + (k - H));
        acc += w.x * c.x + w.y * c.y + w.z * c.z + w.w * c.w;
    }
    __shared__ float sred[4];
    float s = wred_sum(acc);
    int wid = t >> 6, lane = t & 63;
    if (lane == 0) sred[wid] = s;
    __syncthreads();
    if (t == 0) scores[m] = sred[0] + sred[1] + sred[2] + sred[3] + attn_b[m];
}

// ---------- K2: softmax over M=64 scores -> attn_weights (written straight to d_out)
__global__ void k_softmax_m(const float* __restrict__ scores, float* __restrict__ aw_out) {
    int lane = threadIdx.x;  // 64 threads = 1 wave
    float s = scores[lane];
    float mx = s;
#pragma unroll
    for (int o = 32; o >= 1; o >>= 1) mx = fmaxf(mx, __shfl_xor(mx, o));
    float e = expf(s - mx);
    float sum = e;
#pragma unroll
    for (int o = 32; o >= 1; o >>= 1) sum += __shfl_xor(sum, o);
    aw_out[lane] = e / sum;
}

// ---------- K3: attn_applied[h] = sum_m aw[m] * enc[m,h]
__global__ void k_attn_applied(const float* __restrict__ aw, const float* __restrict__ enc,
                               float* __restrict__ attn_applied) {
    int h = blockIdx.x * 256 + threadIdx.x;  // 8 blocks x 256 = 2048
    __shared__ float w[M];
    if (threadIdx.x < M) w[threadIdx.x] = aw[threadIdx.x];
    __syncthreads();
    float acc = 0.f;
#pragma unroll 8
    for (int m = 0; m < M; ++m) acc += w[m] * enc[(size_t)m * H + h];
    attn_applied[h] = acc;
}

// ---------- K4: x[r] = relu(comb_w[r,:] . concat(emb_row, attn_applied) + comb_b[r])
__global__ void k_combine(const int* __restrict__ tok, const float* __restrict__ emb,
                          const float* __restrict__ comb_w, const float* __restrict__ comb_b,
                          const float* __restrict__ aa, float* __restrict__ x_out) {
    int r = (blockIdx.x * blockDim.x + threadIdx.x) >> 6;  // global wave id = row, 2048 rows
    int lane = threadIdx.x & 63;
    const float* erow = emb + (size_t)tok[0] * H;
    const float4* w4 = (const float4*)(comb_w + (size_t)r * 2 * H);
    float acc = 0.f;
#pragma unroll
    for (int it = 0; it < 16; ++it) {
        int i = it * 64 + lane;  // 1024 float4 per row
        float4 w = w4[i];
        int k = i * 4;
        float4 c = (k < H) ? *(const float4*)(erow + k)
                           : *(const float4*)(aa + (k - H));
        acc += w.x * c.x + w.y * c.y + w.z * c.z + w.w * c.w;
    }
    acc = wred_sum(acc);
    if (lane == 0) x_out[r] = fmaxf(acc + comb_b[r], 0.f);
}

// ---------- K5: GRU cell, one wave per output element j
__global__ void k_gru(const float* __restrict__ hidden, const float* __restrict__ w_ih,
                      const float* __restrict__ w_hh, const float* __restrict__ b_ih,
                      const float* __restrict__ b_hh, const float* __restrict__ x,
                      float* __restrict__ h_out) {
    int j = (blockIdx.x * blockDim.x + threadIdx.x) >> 6;  // 2048 rows
    int lane = threadIdx.x & 63;
    const float4* x4 = (const float4*)x;
    const float4* h4 = (const float4*)hidden;
    const float4* wir = (const float4*)(w_ih + (size_t)j * H);
    const float4* wiz = (const float4*)(w_ih + (size_t)(H + j) * H);
    const float4* win = (const float4*)(w_ih + (size_t)(2 * H + j) * H);
    const float4* whr = (const float4*)(w_hh + (size_t)j * H);
    const float4* whz = (const float4*)(w_hh + (size_t)(H + j) * H);
    const float4* whn = (const float4*)(w_hh + (size_t)(2 * H + j) * H);
    float air = 0, aiz = 0, ain = 0, ahr = 0, ahz = 0, ahn = 0;
#pragma unroll
    for (int it = 0; it < 8; ++it) {
        int i = it * 64 + lane;  // 512 float4 per row
        float4 xv = x4[i], hv = h4[i];
        float4 a;
        a = wir[i]; air += a.x * xv.x + a.y * xv.y + a.z * xv.z + a.w * xv.w;
        a = wiz[i]; aiz += a.x * xv.x + a.y * xv.y + a.z * xv.z + a.w * xv.w;
        a = win[i]; ain += a.x * xv.x + a.y * xv.y + a.z * xv.z + a.w * xv.w;
        a = whr[i]; ahr += a.x * hv.x + a.y * hv.y + a.z * hv.z + a.w * hv.w;
        a = whz[i]; ahz += a.x * hv.x + a.y * hv.y + a.z * hv.z + a.w * hv.w;
        a = whn[i]; ahn += a.x * hv.x + a.y * hv.y + a.z * hv.z + a.w * hv.w;
    }
    air = wred_sum(air); aiz = wred_sum(aiz); ain = wred_sum(ain);
    ahr = wred_sum(ahr); ahz = wred_sum(ahz); ahn = wred_sum(ahn);
    if (lane == 0) {
        float r = 1.f / (1.f + expf(-(air + b_ih[j] + ahr + b_hh[j])));
        float z = 1.f / (1.f + expf(-(aiz + b_ih[H + j] + ahz + b_hh[H + j])));
        float n = tanhf(ain + b_ih[2 * H + j] + r * (ahn + b_hh[2 * H + j]));
        h_out[j] = (1.f - z) * n + z * hidden[j];
    }
}

// ---------- K6: logits[v] = out_w[v,:] . h_new + out_b[v]  (the 412 MB GEMV)
__global__ void k_logits(const float* __restrict__ out_w, const float* __restrict__ out_b,
                         const float* __restrict__ hnew, float* __restrict__ logits) {
    int v = (blockIdx.x * blockDim.x + threadIdx.x) >> 6;
    if (v >= V) return;
    int lane = threadIdx.x & 63;
    const float4* w4 = (const float4*)(out_w + (size_t)v * H);
    const float4* h4 = (const float4*)hnew;
    float acc = 0.f;
#pragma unroll
    for (int it = 0; it < 8; ++it) {
        int i = it * 64 + lane;  // 512 float4 per row
        float4 w = w4[i], h = h4[i];
        acc += w.x * h.x + w.y * h.y + w.z * h.z + w.w * h.w;
    }
    acc = wred_sum(acc);
    if (lane == 0) logits[v] = acc + out_b[v];
}

// ---------- K7a: per-block online (max, sumexp) partials over V logits
__global__ void k_lse_part(const float* __restrict__ logits, float* __restrict__ part) {
    int t = threadIdx.x, b = blockIdx.x;  // 64 blocks x 256 threads
    float m = -INFINITY, s = 0.f;
    for (int i = b * 256 + t; i < V; i += 64 * 256) {
        float v = logits[i];
        if (v > m) { s = s * expf(m - v) + 1.f; m = v; }
        else s += expf(v - m);
    }
    __shared__ float sm[256], ss[256];
    sm[t] = m; ss[t] = s;
    __syncthreads();
    for (int o = 128; o >= 1; o >>= 1) {
        if (t < o) {
            float m2 = sm[t + o], s2 = ss[t + o];
            float mm = fmaxf(sm[t], m2);
            ss[t] = ss[t] * expf(sm[t] - mm) + s2 * expf(m2 - mm);
            sm[t] = mm;
        }
        __syncthreads();
    }
    if (t == 0) { part[b] = sm[0]; part[64 + b] = ss[0]; }
}

// ---------- K7b: combine 64 partials -> (gmax, log(sumexp))
__global__ void k_lse_final(const float* __restrict__ part, float* __restrict__ g) {
    int lane = threadIdx.x;  // 64
    float m = part[lane], s = part[64 + lane];
#pragma unroll
    for (int o = 32; o >= 1; o >>= 1) {
        float m2 = __shfl_xor(m, o), s2 = __shfl_xor(s, o);
        float mm = fmaxf(m, m2);
        s = s * expf(m - mm) + s2 * expf(m2 - mm);
        m = mm;
    }
    if (lane == 0) { g[0] = m; g[1] = logf(s); }
}

// ---------- K8: in-place log-softmax
__global__ void k_logsoftmax(float* __restrict__ logits, const float* __restrict__ g) {
    int i = blockIdx.x * 256 + threadIdx.x;
    if (i < V) logits[i] = logits[i] - g[0] - g[1];
}

extern "C" void kernel_launch(void* const* d_in, const int* in_sizes, int n_in,
                              void* d_out, int out_size, void* d_ws, size_t ws_size,
                              hipStream_t stream) {
    const int*   tok     = (const int*)d_in[0];
    const float* hidden  = (const float*)d_in[1];   // [1,1,H]
    const float* enc     = (const float*)d_in[2];   // [M,H]
    const float* emb     = (const float*)d_in[3];   // [V,H]
    const float* attn_w  = (const float*)d_in[4];   // [M,2H]
    const float* attn_b  = (const float*)d_in[5];   // [M]
    const float* comb_w  = (const float*)d_in[6];   // [H,2H]
    const float* comb_b  = (const float*)d_in[7];   // [H]
    const float* w_ih    = (const float*)d_in[8];   // [3H,H]
    const float* w_hh    = (const float*)d_in[9];   // [3H,H]
    const float* b_ih    = (const float*)d_in[10];  // [3H]
    const float* b_hh    = (const float*)d_in[11];  // [3H]
    const float* out_w   = (const float*)d_in[12];  // [V,H]
    const float* out_b   = (const float*)d_in[13];  // [V]

    float* out = (float*)d_out;
    float* logp  = out;             // [V]
    float* hout  = out + V;         // [H]
    float* awout = out + V + H;     // [M]

    float* ws   = (float*)d_ws;
    float* AA   = ws;               // [H]   attn_applied
    float* X    = ws + 2048;        // [H]   relu(combine)
    float* SC   = ws + 4096;        // [M]   raw scores
    float* PART = ws + 4160;        // [128] lse partials (max|sum)
    float* G    = ws + 4288;        // [2]   (gmax, log sumexp)

    k_scores      <<<64,    256, 0, stream>>>(tok, hidden, emb, attn_w, attn_b, SC);
    k_softmax_m   <<<1,     64,  0, stream>>>(SC, awout);
    k_attn_applied<<<8,     256, 0, stream>>>(awout, enc, AA);
    k_combine     <<<512,   256, 0, stream>>>(tok, emb, comb_w, comb_b, AA, X);
    k_gru         <<<512,   256, 0, stream>>>(hidden, w_ih, w_hh, b_ih, b_hh, X, hout);
    k_logits      <<<12565, 256, 0, stream>>>(out_w, out_b, hout, logp);
    k_lse_part    <<<64,    256, 0, stream>>>(logp, PART);
    k_lse_final   <<<1,     64,  0, stream>>>(PART, G);
    k_logsoftmax  <<<197,   256, 0, stream>>>(logp, G);
}